// Round 1
// baseline (2040.645 us; speedup 1.0000x reference)
//
#include <hip/hip_runtime.h>
#include <stdint.h>

#define NIMG 16
#define ATOT 261888
#define TOTC 4768
#define POSTN 1000
#define NMS_THR 0.7f

// 0 = exp-based logistic (XLA LogisticExpander: 1/(1+exp(-x)) w/ Cephes FMA exp)
// 1 = tanh-based (XLA EmitFastTanh, no FMA)
#define SIGMOID_VARIANT 0

__device__ __forceinline__ unsigned sortable_u32(float f) {
  unsigned b = __float_as_uint(f);
  return (b & 0x80000000u) ? ~b : (b | 0x80000000u);
}

// ---- XLA CPU expf replica (Cephes constants, FMA as vsl.MulAdd) ----
__device__ __forceinline__ float exp_xla(float x) {
  float xc = fminf(x, 88.72283935546875f);
  xc = fmaxf(xc, -87.33654022216796875f);
  float n = floorf(fmaf(xc, 1.44269504088896341f, 0.5f));
  float r = fmaf(n, -0.693359375f, xc);
  r = fmaf(n, 2.12194440e-4f, r);
  float y = 1.9875691500e-4f;
  y = fmaf(y, r, 1.3981999507e-3f);
  y = fmaf(y, r, 8.3334519073e-3f);
  y = fmaf(y, r, 4.1665795894e-2f);
  y = fmaf(y, r, 1.6666665459e-1f);
  y = fmaf(y, r, 5.0000001201e-1f);
  float r2 = r * r;
  y = fmaf(y, r2, r);
  y = y + 1.0f;
  return ldexpf(y, (int)n);
}

// ---- XLA EmitFastTanh replica (no FMA) ----
__device__ __forceinline__ float tanh_xla(float x) {
#pragma clang fp contract(off)
  float ax = fabsf(x);
  float xc = fminf(fmaxf(x, -7.90531110763549805f), 7.90531110763549805f);
  float x2 = xc * xc;
  float p = -2.76076847742355e-16f;
  p = x2 * p + 2.00018790482477e-13f;
  p = x2 * p + -8.60467152213735e-11f;
  p = x2 * p + 5.12229709037114e-08f;
  p = x2 * p + 1.48572235717979e-05f;
  p = x2 * p + 6.37261928875436e-04f;
  p = x2 * p + 4.89352455891786e-03f;
  p = xc * p;
  float q = x2 * 1.19825839466702e-06f + 1.18534705686654e-04f;
  q = x2 * q + 2.26843463243900e-03f;
  q = x2 * q + 4.89352518554385e-03f;
  float t = p / q;
  if (ax < 0.0004f) t = x;
  return t;
}

__device__ __forceinline__ float sigmoid_ref(float x) {
#pragma clang fp contract(off)
#if SIGMOID_VARIANT == 0
  float e = exp_xla(-x);
  return 1.0f / (1.0f + e);
#else
  float t = tanh_xla(0.5f * x);
  return 0.5f + 0.5f * t;
#endif
}

// ---- K1: exact per-(img,level) top-k via MSB radix select on raw objectness ----
__global__ void __launch_bounds__(256) k_select(const float* __restrict__ obj,
                                                int* __restrict__ cand,
                                                int* __restrict__ eqbuf) {
  const int LN[5] = {196608, 49152, 12288, 3072, 768};
  const int LO[5] = {0, 196608, 245760, 258048, 261120};
  const int KL[5] = {1000, 1000, 1000, 1000, 768};
  const int CO[5] = {0, 1000, 2000, 3000, 4000};
  int img = blockIdx.x / 5, lvl = blockIdx.x % 5;
  int n = LN[lvl], off = LO[lvl], k = KL[lvl];
  int cbase = img * TOTC + CO[lvl];
  const float* p = obj + (size_t)img * ATOT + off;
  int tid = threadIdx.x;
  if (k == n) {  // level 4: take all
    for (int i = tid; i < n; i += 256) cand[cbase + i] = off + i;
    return;
  }
  __shared__ unsigned hist[256];
  __shared__ unsigned s_pref, s_krem;
  unsigned pref = 0;
  unsigned krem = (unsigned)k;
  for (int round = 0; round < 4; ++round) {
    int shift = 24 - 8 * round;
    hist[tid] = 0;
    __syncthreads();
    for (int i = tid; i < n; i += 256) {
      unsigned u = sortable_u32(p[i]);
      if (round == 0 || (u >> (shift + 8)) == pref)
        atomicAdd(&hist[(u >> shift) & 255u], 1u);
    }
    __syncthreads();
    if (tid == 0) {
      unsigned cum = 0;
      int d = 255;
      for (; d > 0; --d) {
        if (cum + hist[d] >= krem) break;
        cum += hist[d];
      }
      s_pref = (pref << 8) | (unsigned)d;
      s_krem = krem - cum;
    }
    __syncthreads();
    pref = s_pref;
    krem = s_krem;
    __syncthreads();
  }
  // pref = exact key of k-th largest; take all > pref, plus krem equals (lowest idx first)
  __shared__ int cgt, ceq;
  if (tid == 0) { cgt = 0; ceq = 0; }
  __syncthreads();
  int* eq = eqbuf + blockIdx.x * 1024;
  for (int i = tid; i < n; i += 256) {
    unsigned u = sortable_u32(p[i]);
    if (u > pref) {
      int s = atomicAdd(&cgt, 1);
      cand[cbase + s] = off + i;
    } else if (u == pref) {
      int e = atomicAdd(&ceq, 1);
      if (e < 1024) eq[e] = i;
    }
  }
  __syncthreads();
  if (tid == 0) {
    int ne = ceq < 1024 ? ceq : 1024;
    int got = cgt;
    for (int r = 0; r < (int)krem; ++r) {
      int besti = -1, bestv = 0x7fffffff;
      for (int e = 0; e < ne; ++e) {
        int v = eq[e];
        if (v >= 0 && v < bestv) { bestv = v; besti = e; }
      }
      if (besti < 0) break;
      eq[besti] = -1;
      cand[cbase + got + r] = off + bestv;
    }
  }
}

// ---- K2: sort each level's selected slots by (obj desc, idx asc) = lax.top_k order ----
__global__ void __launch_bounds__(1024) k_lvlsort(const float* __restrict__ obj,
                                                  int* __restrict__ cand) {
  const int KL[5] = {1000, 1000, 1000, 1000, 768};
  const int CO[5] = {0, 1000, 2000, 3000, 4000};
  int img = blockIdx.x / 5, lvl = blockIdx.x % 5;
  int k = KL[lvl];
  int cbase = img * TOTC + CO[lvl];
  int tid = threadIdx.x;
  __shared__ unsigned long long sh[1024];
  unsigned long long key = 0ull;
  if (tid < k) {
    int idx = cand[cbase + tid];
    unsigned u = sortable_u32(obj[(size_t)img * ATOT + idx]);
    key = ((unsigned long long)u << 32) | (unsigned)(0xFFFFFFFFu - (unsigned)idx);
  }
  sh[tid] = key;
  __syncthreads();
  for (int kk = 2; kk <= 1024; kk <<= 1)
    for (int j = kk >> 1; j > 0; j >>= 1) {
      int ixj = tid ^ j;
      if (ixj > tid) {
        unsigned long long a = sh[tid], b = sh[ixj];
        bool up2 = ((tid & kk) == 0);
        if ((a < b) == up2) { sh[tid] = b; sh[ixj] = a; }
      }
      __syncthreads();
    }
  if (tid < k) {
    unsigned low = (unsigned)(sh[tid] & 0xFFFFFFFFull);
    cand[cbase + tid] = (int)(0xFFFFFFFFu - low);
  }
}

// ---- K3: gather + sigmoid + BoxCoder decode + clip + valid; per-image max coord ----
__global__ void __launch_bounds__(256) k_decode(const float* __restrict__ obj,
                                                const float* __restrict__ del,
                                                const float* __restrict__ anc,
                                                const int* __restrict__ cand,
                                                float* __restrict__ boxo,
                                                float* __restrict__ keyf,
                                                unsigned* __restrict__ skey,
                                                unsigned* __restrict__ maxcb) {
#pragma clang fp contract(off)
  int img = blockIdx.x;
  int c = blockIdx.y * 256 + threadIdx.x;
  float m = 0.0f;
  if (c < TOTC) {
    int a = cand[img * TOTC + c];
    float o = obj[(size_t)img * ATOT + a];
    float s = sigmoid_ref(o);
    const float* ap = anc + (size_t)a * 4;
    float a0 = ap[0], a1 = ap[1], a2 = ap[2], a3 = ap[3];
    const float* dp = del + ((size_t)img * ATOT + (size_t)a) * 4;
    float dx = dp[0], dy = dp[1], dw = dp[2], dh = dp[3];
    float wa = a2 - a0, ha = a3 - a1;
    float cxa = a0 + 0.5f * wa, cya = a1 + 0.5f * ha;
    dw = fminf(dw, 4.135166556742356f);
    dh = fminf(dh, 4.135166556742356f);
    float cx = dx * wa + cxa;
    float cy = dy * ha + cya;
    float w = exp_xla(dw) * wa;
    float h = exp_xla(dh) * ha;
    float x1 = cx - 0.5f * w, y1 = cy - 0.5f * h;
    float x2 = cx + 0.5f * w, y2 = cy + 0.5f * h;
    x1 = fminf(fmaxf(x1, 0.0f), 1024.0f);
    x2 = fminf(fmaxf(x2, 0.0f), 1024.0f);
    y1 = fminf(fmaxf(y1, 0.0f), 1024.0f);
    y2 = fminf(fmaxf(y2, 0.0f), 1024.0f);
    float ww = x2 - x1, hh = y2 - y1;
    bool valid = (ww >= 1e-3f) && (hh >= 1e-3f) && (s >= 0.0f);
    float kf = valid ? s : -1.0f;
    float4 bx = make_float4(x1, y1, x2, y2);
    *(float4*)(boxo + (size_t)(img * TOTC + c) * 4) = bx;
    keyf[img * TOTC + c] = kf;
    skey[img * TOTC + c] = sortable_u32(kf);
    m = fmaxf(fmaxf(x1, x2), fmaxf(y1, y2));
  }
  __shared__ float red[256];
  red[threadIdx.x] = m;
  __syncthreads();
  for (int s2 = 128; s2 > 0; s2 >>= 1) {
    if (threadIdx.x < s2) red[threadIdx.x] = fmaxf(red[threadIdx.x], red[threadIdx.x + s2]);
    __syncthreads();
  }
  if (threadIdx.x == 0) atomicMax(&maxcb[img], __float_as_uint(red[0]));
}

// ---- K4: per-image global sort: key = (score_sortable, ~slot) desc == ref stable argsort ----
__global__ void __launch_bounds__(1024) k_gsort(const unsigned* __restrict__ skey,
                                                int* __restrict__ ord) {
  int img = blockIdx.x;
  int tid = threadIdx.x;
  __shared__ unsigned long long sh[8192];  // 64 KiB
  for (int i = tid; i < 8192; i += 1024) {
    unsigned long long key = 0ull;
    if (i < TOTC) {
      unsigned u = skey[img * TOTC + i];
      key = ((unsigned long long)u << 32) | (unsigned)(0xFFFFu - i);
    }
    sh[i] = key;
  }
  __syncthreads();
  for (int kk = 2; kk <= 8192; kk <<= 1)
    for (int j = kk >> 1; j > 0; j >>= 1) {
      for (int e = tid; e < 8192; e += 1024) {
        int ixj = e ^ j;
        if (ixj > e) {
          unsigned long long a = sh[e], b = sh[ixj];
          bool up2 = ((e & kk) == 0);
          if ((a < b) == up2) { sh[e] = b; sh[ixj] = a; }
        }
      }
      __syncthreads();
    }
  for (int i = tid; i < TOTC; i += 1024) {
    unsigned low = (unsigned)(sh[i] & 0xFFFFull);
    ord[img * TOTC + i] = (int)(0xFFFFu - low);
  }
}

// ---- K5: build sorted records: offset box (batched_nms trick, exact op order), area, key, orig box ----
__global__ void __launch_bounds__(256) k_srec(const float* __restrict__ boxo,
                                              const float* __restrict__ keyf,
                                              const int* __restrict__ ord,
                                              const unsigned* __restrict__ maxcb,
                                              float* __restrict__ srec) {
#pragma clang fp contract(off)
  int img = blockIdx.x;
  int i = blockIdx.y * 256 + threadIdx.x;
  if (i >= TOTC) return;
  int p = ord[img * TOTC + i];
  int lvl = p / 1000;
  if (lvl > 4) lvl = 4;
  float4 b = *(const float4*)(boxo + (size_t)(img * TOTC + p) * 4);
  float maxc = __uint_as_float(maxcb[img]);
  float off = (float)lvl * (maxc + 1.0f);
  float ox1 = b.x + off, oy1 = b.y + off, ox2 = b.z + off, oy2 = b.w + off;
  float area = (ox2 - ox1) * (oy2 - oy1);
  float kf = keyf[img * TOTC + p];
  float* r = srec + (size_t)(img * TOTC + i) * 12;
  r[0] = ox1; r[1] = oy1; r[2] = ox2; r[3] = oy2;
  r[4] = area; r[5] = kf;
  r[6] = b.x; r[7] = b.y; r[8] = b.z; r[9] = b.w;
  r[10] = 0.0f; r[11] = 0.0f;
}

// ---- K6: greedy NMS, one wave per image, kept boxes in LDS, early exit at 1000 kept ----
__global__ void __launch_bounds__(64) k_nms(const float* __restrict__ srec,
                                            float* __restrict__ out) {
#pragma clang fp contract(off)
  int img = blockIdx.x;
  int lane = threadIdx.x;
  __shared__ float kb[POSTN][4];
  __shared__ float ka[POSTN];
  const float* base = srec + (size_t)img * TOTC * 12;
  float* ob = out + (size_t)img * POSTN * 4;
  float* os = out + (size_t)NIMG * POSTN * 4 + (size_t)img * POSTN;
  int c = 0;
  float4 A = *(const float4*)(base);
  float4 B = *(const float4*)(base + 4);
  float4 C = *(const float4*)(base + 8);
  for (int i = 0; i < TOTC && c < POSTN; ++i) {
    float4 nA = A, nB = B, nC = C;
    if (i + 1 < TOTC) {  // prefetch next record while computing current
      const float* nr = base + (size_t)(i + 1) * 12;
      nA = *(const float4*)(nr);
      nB = *(const float4*)(nr + 4);
      nC = *(const float4*)(nr + 8);
    }
    float ox1 = A.x, oy1 = A.y, ox2 = A.z, oy2 = A.w;
    float ai = B.x, key = B.y;
    bool sup = false;
    for (int j = lane; j < c; j += 64) {
      float ltx = fmaxf(ox1, kb[j][0]);
      float lty = fmaxf(oy1, kb[j][1]);
      float rbx = fminf(ox2, kb[j][2]);
      float rby = fminf(oy2, kb[j][3]);
      float w = fmaxf(rbx - ltx, 0.0f);
      float h = fmaxf(rby - lty, 0.0f);
      float inter = w * h;
      float uni = (ai + ka[j]) - inter;
      float iou = (uni > 0.0f) ? (inter / uni) : 0.0f;
      if (iou > NMS_THR) sup = true;
    }
    bool any = (__ballot(sup) != 0ull);
    bool valid = key > -0.5f;  // invalid candidates carry key == -1.0f
    if (valid && !any) {
      if (lane == 0) {
        kb[c][0] = ox1; kb[c][1] = oy1; kb[c][2] = ox2; kb[c][3] = oy2;
        ka[c] = ai;
        ob[(size_t)c * 4 + 0] = B.z;
        ob[(size_t)c * 4 + 1] = B.w;
        ob[(size_t)c * 4 + 2] = C.x;
        ob[(size_t)c * 4 + 3] = C.y;
        os[c] = key;
      }
      ++c;
      __syncthreads();
    }
    A = nA; B = nB; C = nC;
  }
}

extern "C" void kernel_launch(void* const* d_in, const int* in_sizes, int n_in,
                              void* d_out, int out_size, void* d_ws, size_t ws_size,
                              hipStream_t stream) {
  const float* obj = (const float*)d_in[0];
  const float* del = (const float*)d_in[1];
  const float* anc = (const float*)d_in[2];
  float* out = (float*)d_out;

  char* w = (char*)d_ws;
  size_t o = 0;
  auto carve = [&](size_t bytes) -> char* {
    char* p = w + o;
    o = (o + bytes + 255) & ~(size_t)255;
    return p;
  };
  int* cand = (int*)carve((size_t)NIMG * TOTC * 4);
  unsigned* skey = (unsigned*)carve((size_t)NIMG * TOTC * 4);
  float* keyf = (float*)carve((size_t)NIMG * TOTC * 4);
  int* ord = (int*)carve((size_t)NIMG * TOTC * 4);
  float* boxo = (float*)carve((size_t)NIMG * TOTC * 16);
  float* srec = (float*)carve((size_t)NIMG * TOTC * 48);
  unsigned* maxcb = (unsigned*)carve(64);
  int* eqbuf = (int*)carve((size_t)80 * 1024 * 4);

  hipMemsetAsync(d_out, 0, (size_t)out_size * sizeof(float), stream);
  hipMemsetAsync(maxcb, 0, 16 * sizeof(unsigned), stream);

  k_select<<<80, 256, 0, stream>>>(obj, cand, eqbuf);
  k_lvlsort<<<80, 1024, 0, stream>>>(obj, cand);
  k_decode<<<dim3(16, (TOTC + 255) / 256), 256, 0, stream>>>(obj, del, anc, cand, boxo, keyf, skey, maxcb);
  k_gsort<<<16, 1024, 0, stream>>>(skey, ord);
  k_srec<<<dim3(16, (TOTC + 255) / 256), 256, 0, stream>>>(boxo, keyf, ord, maxcb, srec);
  k_nms<<<16, 64, 0, stream>>>(srec, out);
}

// Round 2
// 1912.084 us; speedup vs baseline: 1.0672x; 1.0672x over previous
//
#include <hip/hip_runtime.h>
#include <stdint.h>

#define NIMG 16
#define ATOT 261888
#define TOTC 4768
#define POSTN 1000
#define NMS_THR 0.7f
#define ROWQ 75  // qwords per suppression-matrix row (4768 bits -> 74.5 -> 75)

// 0 = exp-based logistic (XLA LogisticExpander: 1/(1+exp(-x)) w/ Cephes FMA exp)  [VERIFIED absmax 0.0]
#define SIGMOID_VARIANT 0

__device__ __forceinline__ unsigned sortable_u32(float f) {
  unsigned b = __float_as_uint(f);
  return (b & 0x80000000u) ? ~b : (b | 0x80000000u);
}

// ---- XLA CPU expf replica (Cephes constants, FMA as vsl.MulAdd) ----
__device__ __forceinline__ float exp_xla(float x) {
  float xc = fminf(x, 88.72283935546875f);
  xc = fmaxf(xc, -87.33654022216796875f);
  float n = floorf(fmaf(xc, 1.44269504088896341f, 0.5f));
  float r = fmaf(n, -0.693359375f, xc);
  r = fmaf(n, 2.12194440e-4f, r);
  float y = 1.9875691500e-4f;
  y = fmaf(y, r, 1.3981999507e-3f);
  y = fmaf(y, r, 8.3334519073e-3f);
  y = fmaf(y, r, 4.1665795894e-2f);
  y = fmaf(y, r, 1.6666665459e-1f);
  y = fmaf(y, r, 5.0000001201e-1f);
  float r2 = r * r;
  y = fmaf(y, r2, r);
  y = y + 1.0f;
  return ldexpf(y, (int)n);
}

__device__ __forceinline__ float sigmoid_ref(float x) {
#pragma clang fp contract(off)
  float e = exp_xla(-x);
  return 1.0f / (1.0f + e);
}

// ---- K1: exact per-(img,level) top-k via MSB radix select on raw objectness ----
__global__ void __launch_bounds__(256) k_select(const float* __restrict__ obj,
                                                int* __restrict__ cand,
                                                int* __restrict__ eqbuf) {
  const int LN[5] = {196608, 49152, 12288, 3072, 768};
  const int LO[5] = {0, 196608, 245760, 258048, 261120};
  const int KL[5] = {1000, 1000, 1000, 1000, 768};
  const int CO[5] = {0, 1000, 2000, 3000, 4000};
  int img = blockIdx.x / 5, lvl = blockIdx.x % 5;
  int n = LN[lvl], off = LO[lvl], k = KL[lvl];
  int cbase = img * TOTC + CO[lvl];
  const float* p = obj + (size_t)img * ATOT + off;
  int tid = threadIdx.x;
  if (k == n) {  // level 4: take all
    for (int i = tid; i < n; i += 256) cand[cbase + i] = off + i;
    return;
  }
  __shared__ unsigned hist[256];
  __shared__ unsigned s_pref, s_krem;
  unsigned pref = 0;
  unsigned krem = (unsigned)k;
  for (int round = 0; round < 4; ++round) {
    int shift = 24 - 8 * round;
    hist[tid] = 0;
    __syncthreads();
    for (int i = tid; i < n; i += 256) {
      unsigned u = sortable_u32(p[i]);
      if (round == 0 || (u >> (shift + 8)) == pref)
        atomicAdd(&hist[(u >> shift) & 255u], 1u);
    }
    __syncthreads();
    if (tid == 0) {
      unsigned cum = 0;
      int d = 255;
      for (; d > 0; --d) {
        if (cum + hist[d] >= krem) break;
        cum += hist[d];
      }
      s_pref = (pref << 8) | (unsigned)d;
      s_krem = krem - cum;
    }
    __syncthreads();
    pref = s_pref;
    krem = s_krem;
    __syncthreads();
  }
  __shared__ int cgt, ceq;
  if (tid == 0) { cgt = 0; ceq = 0; }
  __syncthreads();
  int* eq = eqbuf + blockIdx.x * 1024;
  for (int i = tid; i < n; i += 256) {
    unsigned u = sortable_u32(p[i]);
    if (u > pref) {
      int s = atomicAdd(&cgt, 1);
      cand[cbase + s] = off + i;
    } else if (u == pref) {
      int e = atomicAdd(&ceq, 1);
      if (e < 1024) eq[e] = i;
    }
  }
  __syncthreads();
  if (tid == 0) {
    int ne = ceq < 1024 ? ceq : 1024;
    int got = cgt;
    for (int r = 0; r < (int)krem; ++r) {
      int besti = -1, bestv = 0x7fffffff;
      for (int e = 0; e < ne; ++e) {
        int v = eq[e];
        if (v >= 0 && v < bestv) { bestv = v; besti = e; }
      }
      if (besti < 0) break;
      eq[besti] = -1;
      cand[cbase + got + r] = off + bestv;
    }
  }
}

// ---- K2: sort each level's selected slots by (obj desc, idx asc) = lax.top_k order ----
__global__ void __launch_bounds__(1024) k_lvlsort(const float* __restrict__ obj,
                                                  int* __restrict__ cand) {
  const int KL[5] = {1000, 1000, 1000, 1000, 768};
  const int CO[5] = {0, 1000, 2000, 3000, 4000};
  int img = blockIdx.x / 5, lvl = blockIdx.x % 5;
  int k = KL[lvl];
  int cbase = img * TOTC + CO[lvl];
  int tid = threadIdx.x;
  __shared__ unsigned long long sh[1024];
  unsigned long long key = 0ull;
  if (tid < k) {
    int idx = cand[cbase + tid];
    unsigned u = sortable_u32(obj[(size_t)img * ATOT + idx]);
    key = ((unsigned long long)u << 32) | (unsigned)(0xFFFFFFFFu - (unsigned)idx);
  }
  sh[tid] = key;
  __syncthreads();
  for (int kk = 2; kk <= 1024; kk <<= 1)
    for (int j = kk >> 1; j > 0; j >>= 1) {
      int ixj = tid ^ j;
      if (ixj > tid) {
        unsigned long long a = sh[tid], b = sh[ixj];
        bool up2 = ((tid & kk) == 0);
        if ((a < b) == up2) { sh[tid] = b; sh[ixj] = a; }
      }
      __syncthreads();
    }
  if (tid < k) {
    unsigned low = (unsigned)(sh[tid] & 0xFFFFFFFFull);
    cand[cbase + tid] = (int)(0xFFFFFFFFu - low);
  }
}

// ---- K3: gather + sigmoid + BoxCoder decode + clip + valid; per-image max coord ----
__global__ void __launch_bounds__(256) k_decode(const float* __restrict__ obj,
                                                const float* __restrict__ del,
                                                const float* __restrict__ anc,
                                                const int* __restrict__ cand,
                                                float* __restrict__ boxo,
                                                float* __restrict__ keyf,
                                                unsigned* __restrict__ skey,
                                                unsigned* __restrict__ maxcb) {
#pragma clang fp contract(off)
  int img = blockIdx.x;
  int c = blockIdx.y * 256 + threadIdx.x;
  float m = 0.0f;
  if (c < TOTC) {
    int a = cand[img * TOTC + c];
    float o = obj[(size_t)img * ATOT + a];
    float s = sigmoid_ref(o);
    const float* ap = anc + (size_t)a * 4;
    float a0 = ap[0], a1 = ap[1], a2 = ap[2], a3 = ap[3];
    const float* dp = del + ((size_t)img * ATOT + (size_t)a) * 4;
    float dx = dp[0], dy = dp[1], dw = dp[2], dh = dp[3];
    float wa = a2 - a0, ha = a3 - a1;
    float cxa = a0 + 0.5f * wa, cya = a1 + 0.5f * ha;
    dw = fminf(dw, 4.135166556742356f);
    dh = fminf(dh, 4.135166556742356f);
    float cx = dx * wa + cxa;
    float cy = dy * ha + cya;
    float w = exp_xla(dw) * wa;
    float h = exp_xla(dh) * ha;
    float x1 = cx - 0.5f * w, y1 = cy - 0.5f * h;
    float x2 = cx + 0.5f * w, y2 = cy + 0.5f * h;
    x1 = fminf(fmaxf(x1, 0.0f), 1024.0f);
    x2 = fminf(fmaxf(x2, 0.0f), 1024.0f);
    y1 = fminf(fmaxf(y1, 0.0f), 1024.0f);
    y2 = fminf(fmaxf(y2, 0.0f), 1024.0f);
    float ww = x2 - x1, hh = y2 - y1;
    bool valid = (ww >= 1e-3f) && (hh >= 1e-3f) && (s >= 0.0f);
    float kf = valid ? s : -1.0f;
    float4 bx = make_float4(x1, y1, x2, y2);
    *(float4*)(boxo + (size_t)(img * TOTC + c) * 4) = bx;
    keyf[img * TOTC + c] = kf;
    skey[img * TOTC + c] = sortable_u32(kf);
    m = fmaxf(fmaxf(x1, x2), fmaxf(y1, y2));
  }
  __shared__ float red[256];
  red[threadIdx.x] = m;
  __syncthreads();
  for (int s2 = 128; s2 > 0; s2 >>= 1) {
    if (threadIdx.x < s2) red[threadIdx.x] = fmaxf(red[threadIdx.x], red[threadIdx.x + s2]);
    __syncthreads();
  }
  if (threadIdx.x == 0) atomicMax(&maxcb[img], __float_as_uint(red[0]));
}

// ---- K4: per-image global sort: key = (score_sortable, ~slot) desc == ref stable argsort ----
__global__ void __launch_bounds__(1024) k_gsort(const unsigned* __restrict__ skey,
                                                int* __restrict__ ord) {
  int img = blockIdx.x;
  int tid = threadIdx.x;
  __shared__ unsigned long long sh[8192];  // 64 KiB
  for (int i = tid; i < 8192; i += 1024) {
    unsigned long long key = 0ull;
    if (i < TOTC) {
      unsigned u = skey[img * TOTC + i];
      key = ((unsigned long long)u << 32) | (unsigned)(0xFFFFu - i);
    }
    sh[i] = key;
  }
  __syncthreads();
  for (int kk = 2; kk <= 8192; kk <<= 1)
    for (int j = kk >> 1; j > 0; j >>= 1) {
      for (int e = tid; e < 8192; e += 1024) {
        int ixj = e ^ j;
        if (ixj > e) {
          unsigned long long a = sh[e], b = sh[ixj];
          bool up2 = ((e & kk) == 0);
          if ((a < b) == up2) { sh[e] = b; sh[ixj] = a; }
        }
      }
      __syncthreads();
    }
  for (int i = tid; i < TOTC; i += 1024) {
    unsigned low = (unsigned)(sh[i] & 0xFFFFull);
    ord[img * TOTC + i] = (int)(0xFFFFu - low);
  }
}

// ---- K5: build sorted records: offset box (batched_nms trick, exact op order), area, key, orig box ----
__global__ void __launch_bounds__(256) k_srec(const float* __restrict__ boxo,
                                              const float* __restrict__ keyf,
                                              const int* __restrict__ ord,
                                              const unsigned* __restrict__ maxcb,
                                              float* __restrict__ srec) {
#pragma clang fp contract(off)
  int img = blockIdx.x;
  int i = blockIdx.y * 256 + threadIdx.x;
  if (i >= TOTC) return;
  int p = ord[img * TOTC + i];
  int lvl = p / 1000;
  if (lvl > 4) lvl = 4;
  float4 b = *(const float4*)(boxo + (size_t)(img * TOTC + p) * 4);
  float maxc = __uint_as_float(maxcb[img]);
  float off = (float)lvl * (maxc + 1.0f);
  float ox1 = b.x + off, oy1 = b.y + off, ox2 = b.z + off, oy2 = b.w + off;
  float area = (ox2 - ox1) * (oy2 - oy1);
  float kf = keyf[img * TOTC + p];
  float* r = srec + (size_t)(img * TOTC + i) * 12;
  r[0] = ox1; r[1] = oy1; r[2] = ox2; r[3] = oy2;
  r[4] = area; r[5] = kf;
  r[6] = b.x; r[7] = b.y; r[8] = b.z; r[9] = b.w;
  r[10] = 0.0f; r[11] = 0.0f;
}

// ---- K6a: pairwise suppression bit-matrix. bit j of row i  <=>  IoU(i,j) > 0.7 (exact ref arithmetic).
// Only chunks jc >= itile*4 (at/above each block's diagonal tile) are written; lower chunks stay
// garbage — provably never consulted by k_resolve before they are dead (w(i0) >= tilebase(i') for
// every earlier-accepted i').
__global__ void __launch_bounds__(256) k_iou(const float* __restrict__ srec,
                                             unsigned long long* __restrict__ mat,
                                             unsigned long long* __restrict__ validw) {
#pragma clang fp contract(off)
  const int img = blockIdx.x;
  const int itile = blockIdx.y;
  const int tid = threadIdx.x;
  const int i = itile * 256 + tid;
  const int lane = tid & 63;
  const float* sb = srec + (size_t)img * TOTC * 12;
  float ix1 = 0, iy1 = 0, ix2 = 0, iy2 = 0, ia = 0;
  bool vi = false;
  if (i < TOTC) {
    const float* r = sb + (size_t)i * 12;
    float4 b = *(const float4*)r;
    ix1 = b.x; iy1 = b.y; ix2 = b.z; iy2 = b.w;
    ia = r[4];
    vi = r[5] > -0.5f;
  }
  unsigned long long vb = __ballot(vi);
  if (lane == 0 && (i >> 6) < ROWQ) validw[img * ROWQ + (i >> 6)] = vb;

  unsigned long long* rowp = mat + ((size_t)img * TOTC + (size_t)(i < TOTC ? i : 0)) * ROWQ;
  const int jc0 = itile * 4;

  auto loadj = [&](int jc, float& jx1, float& jy1, float& jx2, float& jy2, float& ja) {
    int j = jc * 64 + lane;
    if (j < TOTC) {
      const float* r = sb + (size_t)j * 12;
      float4 b = *(const float4*)r;
      jx1 = b.x; jy1 = b.y; jx2 = b.z; jy2 = b.w;
      ja = r[4];
    } else {
      jx1 = 1e30f; jy1 = 1e30f; jx2 = -1e30f; jy2 = -1e30f; ja = 0.0f;
    }
  };
  float cx1, cy1, cx2, cy2, ca;
  loadj(jc0, cx1, cy1, cx2, cy2, ca);
  for (int jc = jc0; jc < ROWQ; ++jc) {
    float nx1, ny1, nx2, ny2, na;
    loadj(jc + 1, nx1, ny1, nx2, ny2, na);  // prefetch next chunk (j>=TOTC -> inert box)
    unsigned long long bits = 0ull;
    for (int b = 0; b < 64; ++b) {
      float jx1 = __shfl(cx1, b), jy1 = __shfl(cy1, b);
      float jx2 = __shfl(cx2, b), jy2 = __shfl(cy2, b);
      float ja = __shfl(ca, b);
      float ltx = fmaxf(ix1, jx1), lty = fmaxf(iy1, jy1);
      float rbx = fminf(ix2, jx2), rby = fminf(iy2, jy2);
      float w = fmaxf(rbx - ltx, 0.0f), h = fmaxf(rby - lty, 0.0f);
      float inter = w * h;
      float uni = (ia + ja) - inter;
      bool sup = (uni > 0.0f) && (inter / uni > NMS_THR);
      if (sup) bits |= (1ull << b);
    }
    if (i < TOTC) rowp[jc] = bits;
    cx1 = nx1; cy1 = ny1; cx2 = nx2; cy2 = ny2; ca = na;
  }
}

// ---- K6b: greedy resolve over bitmasks, one wave per image, depth-3 row prefetch pipeline ----
__global__ void __launch_bounds__(64) k_resolve(const unsigned long long* __restrict__ mat,
                                                const unsigned long long* __restrict__ validw,
                                                const float* __restrict__ srec,
                                                float* __restrict__ out) {
  const int img = blockIdx.x;
  const int lane = threadIdx.x;
  __shared__ unsigned long long rem[80];
  __shared__ unsigned long long vw[80];
  for (int t = lane; t < 80; t += 64) {
    rem[t] = 0ull;
    vw[t] = (t < ROWQ) ? validw[img * ROWQ + t] : 0ull;
  }
  __syncthreads();
  const unsigned long long* matb = mat + (size_t)img * TOTC * ROWQ;
  const float* sb = srec + (size_t)img * TOTC * 12;
  float* ob = out + (size_t)img * POSTN * 4;
  float* os = out + (size_t)NIMG * POSTN * 4 + (size_t)img * POSTN;

  int vwi = 0;
  unsigned long long vbits = vw[0];
  auto nextv = [&]() -> int {  // next valid candidate index (uniform across lanes)
    while (vbits == 0ull) {
      if (++vwi >= ROWQ) return -1;
      vbits = vw[vwi];
    }
    int b = __builtin_ctzll(vbits);
    vbits &= vbits - 1ull;
    return vwi * 64 + b;
  };
  auto issue = [&](int i, unsigned long long& m0, unsigned long long& m1, float& od) {
    m0 = 0ull; m1 = 0ull; od = 0.0f;
    if (i < 0) return;
    const unsigned long long* row = matb + (size_t)i * ROWQ;
    m0 = row[lane];
    if (lane < ROWQ - 64) m1 = row[64 + lane];
    const float* rec = sb + (size_t)i * 12;
    if (lane < 4) od = rec[6 + lane];
    else if (lane == 4) od = rec[5];
  };
  int i0 = nextv(), i1, i2;
  unsigned long long a0, a1, b0, b1, c0, c1;
  float o0, o1, o2;
  issue(i0, a0, a1, o0);
  i1 = nextv(); issue(i1, b0, b1, o1);
  i2 = nextv(); issue(i2, c0, c1, o2);
  int c = 0;
  while (i0 >= 0 && c < POSTN) {
    int w = i0 >> 6;
    unsigned long long bit = 1ull << (i0 & 63);
    if (!(rem[w] & bit)) {  // uniform branch (broadcast LDS read)
      rem[lane] |= a0;
      if (lane < ROWQ - 64) rem[64 + lane] |= a1;
      if (lane < 4) ob[(size_t)c * 4 + lane] = o0;
      else if (lane == 4) os[c] = o0;
      __syncthreads();
      ++c;
    }
    i0 = i1; a0 = b0; a1 = b1; o0 = o1;
    i1 = i2; b0 = c0; b1 = c1; o1 = o2;
    i2 = nextv(); issue(i2, c0, c1, o2);
  }
}

// ---- K6 (fallback): serial greedy NMS, used only if workspace is too small for the matrix ----
__global__ void __launch_bounds__(64) k_nms(const float* __restrict__ srec,
                                            float* __restrict__ out) {
#pragma clang fp contract(off)
  int img = blockIdx.x;
  int lane = threadIdx.x;
  __shared__ float kb[POSTN][4];
  __shared__ float ka[POSTN];
  const float* base = srec + (size_t)img * TOTC * 12;
  float* ob = out + (size_t)img * POSTN * 4;
  float* os = out + (size_t)NIMG * POSTN * 4 + (size_t)img * POSTN;
  int c = 0;
  float4 A = *(const float4*)(base);
  float4 B = *(const float4*)(base + 4);
  float4 C = *(const float4*)(base + 8);
  for (int i = 0; i < TOTC && c < POSTN; ++i) {
    float4 nA = A, nB = B, nC = C;
    if (i + 1 < TOTC) {
      const float* nr = base + (size_t)(i + 1) * 12;
      nA = *(const float4*)(nr);
      nB = *(const float4*)(nr + 4);
      nC = *(const float4*)(nr + 8);
    }
    float ox1 = A.x, oy1 = A.y, ox2 = A.z, oy2 = A.w;
    float ai = B.x, key = B.y;
    bool sup = false;
    for (int j = lane; j < c; j += 64) {
      float ltx = fmaxf(ox1, kb[j][0]);
      float lty = fmaxf(oy1, kb[j][1]);
      float rbx = fminf(ox2, kb[j][2]);
      float rby = fminf(oy2, kb[j][3]);
      float w = fmaxf(rbx - ltx, 0.0f);
      float h = fmaxf(rby - lty, 0.0f);
      float inter = w * h;
      float uni = (ai + ka[j]) - inter;
      float iou = (uni > 0.0f) ? (inter / uni) : 0.0f;
      if (iou > NMS_THR) sup = true;
    }
    bool any = (__ballot(sup) != 0ull);
    bool valid = key > -0.5f;
    if (valid && !any) {
      if (lane == 0) {
        kb[c][0] = ox1; kb[c][1] = oy1; kb[c][2] = ox2; kb[c][3] = oy2;
        ka[c] = ai;
        ob[(size_t)c * 4 + 0] = B.z;
        ob[(size_t)c * 4 + 1] = B.w;
        ob[(size_t)c * 4 + 2] = C.x;
        ob[(size_t)c * 4 + 3] = C.y;
        os[c] = key;
      }
      ++c;
      __syncthreads();
    }
    A = nA; B = nB; C = nC;
  }
}

extern "C" void kernel_launch(void* const* d_in, const int* in_sizes, int n_in,
                              void* d_out, int out_size, void* d_ws, size_t ws_size,
                              hipStream_t stream) {
  const float* obj = (const float*)d_in[0];
  const float* del = (const float*)d_in[1];
  const float* anc = (const float*)d_in[2];
  float* out = (float*)d_out;

  char* w = (char*)d_ws;
  size_t o = 0;
  auto carve = [&](size_t bytes) -> char* {
    char* p = w + o;
    o = (o + bytes + 255) & ~(size_t)255;
    return p;
  };
  int* cand = (int*)carve((size_t)NIMG * TOTC * 4);
  unsigned* skey = (unsigned*)carve((size_t)NIMG * TOTC * 4);
  float* keyf = (float*)carve((size_t)NIMG * TOTC * 4);
  int* ord = (int*)carve((size_t)NIMG * TOTC * 4);
  float* boxo = (float*)carve((size_t)NIMG * TOTC * 16);
  float* srec = (float*)carve((size_t)NIMG * TOTC * 48);
  unsigned* maxcb = (unsigned*)carve(64);
  int* eqbuf = (int*)carve((size_t)80 * 1024 * 4);
  unsigned long long* validw = (unsigned long long*)carve((size_t)NIMG * ROWQ * 8);
  unsigned long long* mat = (unsigned long long*)carve((size_t)NIMG * TOTC * ROWQ * 8);
  bool fast = (ws_size >= o);

  hipMemsetAsync(d_out, 0, (size_t)out_size * sizeof(float), stream);
  hipMemsetAsync(maxcb, 0, 16 * sizeof(unsigned), stream);

  k_select<<<80, 256, 0, stream>>>(obj, cand, eqbuf);
  k_lvlsort<<<80, 1024, 0, stream>>>(obj, cand);
  k_decode<<<dim3(16, (TOTC + 255) / 256), 256, 0, stream>>>(obj, del, anc, cand, boxo, keyf, skey, maxcb);
  k_gsort<<<16, 1024, 0, stream>>>(skey, ord);
  k_srec<<<dim3(16, (TOTC + 255) / 256), 256, 0, stream>>>(boxo, keyf, ord, maxcb, srec);
  if (fast) {
    k_iou<<<dim3(16, (TOTC + 255) / 256), 256, 0, stream>>>(srec, mat, validw);
    k_resolve<<<16, 64, 0, stream>>>(mat, validw, srec, out);
  } else {
    k_nms<<<16, 64, 0, stream>>>(srec, out);
  }
}

// Round 3
// 1417.484 us; speedup vs baseline: 1.4396x; 1.3489x over previous
//
#include <hip/hip_runtime.h>
#include <stdint.h>

#define NIMG 16
#define ATOT 261888
#define TOTC 4768
#define POSTN 1000
#define NMS_THR 0.7f
#define ROWQ 75   // qwords per suppression-matrix row (4768 bits -> 75)
#define EQCAP 8192

__device__ __forceinline__ unsigned sortable_u32(float f) {
  unsigned b = __float_as_uint(f);
  return (b & 0x80000000u) ? ~b : (b | 0x80000000u);
}

// ---- XLA CPU expf replica (Cephes constants, FMA as vsl.MulAdd)  [VERIFIED absmax 0.0] ----
__device__ __forceinline__ float exp_xla(float x) {
  float xc = fminf(x, 88.72283935546875f);
  xc = fmaxf(xc, -87.33654022216796875f);
  float n = floorf(fmaf(xc, 1.44269504088896341f, 0.5f));
  float r = fmaf(n, -0.693359375f, xc);
  r = fmaf(n, 2.12194440e-4f, r);
  float y = 1.9875691500e-4f;
  y = fmaf(y, r, 1.3981999507e-3f);
  y = fmaf(y, r, 8.3334519073e-3f);
  y = fmaf(y, r, 4.1665795894e-2f);
  y = fmaf(y, r, 1.6666665459e-1f);
  y = fmaf(y, r, 5.0000001201e-1f);
  float r2 = r * r;
  y = fmaf(y, r2, r);
  y = y + 1.0f;
  return ldexpf(y, (int)n);
}

__device__ __forceinline__ float sigmoid_ref(float x) {
#pragma clang fp contract(off)
  float e = exp_xla(-x);
  return 1.0f / (1.0f + e);
}

// Block mapping for selection passes: 17 chunks per image over levels 0..3.
// b<12: lvl0 chunk b (16384) | b<15: lvl1 chunk b-12 (16384) | b==15: lvl2 (12288) | b==16: lvl3 (3072)
__device__ __forceinline__ void chunk_map(int b, int& lvl, int& start, int& cnt) {
  if (b < 12)      { lvl = 0; start = b * 16384;        cnt = 16384; }
  else if (b < 15) { lvl = 1; start = (b - 12) * 16384; cnt = 16384; }
  else if (b == 15){ lvl = 2; start = 0;                cnt = 12288; }
  else             { lvl = 3; start = 0;                cnt = 3072;  }
}
__constant__ int d_LO[5] = {0, 196608, 245760, 258048, 261120};
__constant__ int d_CO[5] = {0, 1000, 2000, 3000, 4000};

// ---- S1: per-(img,lvl) 256-bin histogram of top-8 sortable bits (float4 loads, LDS agg) ----
__global__ void __launch_bounds__(256) k_hist(const float* __restrict__ obj,
                                              unsigned* __restrict__ hist) {
  int img = blockIdx.x / 17, b = blockIdx.x % 17;
  int lvl, start, cnt;
  chunk_map(b, lvl, start, cnt);
  const float4* p4 = (const float4*)(obj + (size_t)img * ATOT + d_LO[lvl] + start);
  __shared__ unsigned h[256];
  h[threadIdx.x] = 0;
  __syncthreads();
  int nv = cnt >> 2;
  for (int i = threadIdx.x; i < nv; i += 256) {
    float4 v = p4[i];
    atomicAdd(&h[sortable_u32(v.x) >> 24], 1u);
    atomicAdd(&h[sortable_u32(v.y) >> 24], 1u);
    atomicAdd(&h[sortable_u32(v.z) >> 24], 1u);
    atomicAdd(&h[sortable_u32(v.w) >> 24], 1u);
  }
  __syncthreads();
  unsigned* gh = hist + (img * 4 + lvl) * 256;
  if (h[threadIdx.x]) atomicAdd(&gh[threadIdx.x], h[threadIdx.x]);
}

// ---- S2: per-(img,lvl) threshold bucket d0 + krem (radix round-0 semantics) ----
__global__ void __launch_bounds__(64) k_thresh(const unsigned* __restrict__ hist,
                                               unsigned* __restrict__ thr) {
  int il = blockIdx.x;
  if (threadIdx.x != 0) return;
  const unsigned* h = hist + il * 256;
  unsigned krem = 1000, cum = 0;
  int d = 255;
  for (; d > 0; --d) {
    if (cum + h[d] >= krem) break;
    cum += h[d];
  }
  thr[il * 2] = (unsigned)d;
  thr[il * 2 + 1] = krem - cum;
}

// ---- S3: emit. bucket>d0 -> cand (count < k guaranteed); bucket==d0 -> eq-list; lvl4 copy ----
__global__ void __launch_bounds__(256) k_emit(const float* __restrict__ obj,
                                              const unsigned* __restrict__ thr,
                                              int* __restrict__ cand,
                                              int* __restrict__ eqbuf,
                                              unsigned* __restrict__ cnt) {
  int img = blockIdx.x / 18, b = blockIdx.x % 18;
  if (b == 17) {  // level 4: k == n, take all
    for (int i = threadIdx.x; i < 768; i += 256)
      cand[img * TOTC + d_CO[4] + i] = d_LO[4] + i;
    return;
  }
  int lvl, start, cntn;
  chunk_map(b, lvl, start, cntn);
  int il = img * 4 + lvl;
  unsigned d0 = thr[il * 2];
  int gbase = d_LO[lvl] + start;
  const float4* p4 = (const float4*)(obj + (size_t)img * ATOT + gbase);
  int nv = cntn >> 2;
  int cbase = img * TOTC + d_CO[lvl];
  for (int i = threadIdx.x; i < nv; i += 256) {
    float4 v = p4[i];
    float vv[4] = {v.x, v.y, v.z, v.w};
#pragma unroll
    for (int c4 = 0; c4 < 4; ++c4) {
      unsigned u = sortable_u32(vv[c4]);
      unsigned d = u >> 24;
      if (d >= d0) {
        int gidx = gbase + i * 4 + c4;
        if (d > d0) {
          int s = atomicAdd(&cnt[il * 2], 1u);
          cand[cbase + s] = gidx;
        } else {
          int e = atomicAdd(&cnt[il * 2 + 1], 1u);
          if (e < EQCAP) eqbuf[il * EQCAP + e] = gidx;
        }
      }
    }
  }
}

// ---- S4: refine eq-bucket with radix rounds 1-3, emit >pref then krem lowest-index ties ----
__global__ void __launch_bounds__(256) k_refine(const float* __restrict__ obj,
                                                const unsigned* __restrict__ thr,
                                                const int* __restrict__ eqbuf,
                                                const unsigned* __restrict__ cnt,
                                                int* __restrict__ cand) {
  int il = blockIdx.x;
  int img = il >> 2, lvl = il & 3;
  unsigned pref = thr[il * 2];
  unsigned krem = thr[il * 2 + 1];
  int neq = min((int)cnt[il * 2 + 1], EQCAP);
  int cgt = (int)cnt[il * 2];
  const float* p = obj + (size_t)img * ATOT;
  const int* eq = eqbuf + il * EQCAP;
  int cbase = img * TOTC + d_CO[lvl];
  __shared__ unsigned h[256];
  __shared__ unsigned s_pref, s_krem;
  for (int round = 1; round < 4; ++round) {
    int shift = 24 - 8 * round;
    h[threadIdx.x] = 0;
    __syncthreads();
    for (int e = threadIdx.x; e < neq; e += 256) {
      unsigned u = sortable_u32(p[eq[e]]);
      if ((u >> (shift + 8)) == pref) atomicAdd(&h[(u >> shift) & 255u], 1u);
    }
    __syncthreads();
    if (threadIdx.x == 0) {
      unsigned cum = 0;
      int d = 255;
      for (; d > 0; --d) {
        if (cum + h[d] >= krem) break;
        cum += h[d];
      }
      s_pref = (pref << 8) | (unsigned)d;
      s_krem = krem - cum;
    }
    __syncthreads();
    pref = s_pref;
    krem = s_krem;
    __syncthreads();
  }
  __shared__ int cg2, ce2;
  __shared__ int eqi[1024];
  if (threadIdx.x == 0) { cg2 = 0; ce2 = 0; }
  __syncthreads();
  for (int e = threadIdx.x; e < neq; e += 256) {
    int gidx = eq[e];
    unsigned u = sortable_u32(p[gidx]);
    if (u > pref) {
      int s = atomicAdd(&cg2, 1);
      cand[cbase + cgt + s] = gidx;
    } else if (u == pref) {
      int s2 = atomicAdd(&ce2, 1);
      if (s2 < 1024) eqi[s2] = gidx;
    }
  }
  __syncthreads();
  if (threadIdx.x == 0) {
    int ne = ce2 < 1024 ? ce2 : 1024;
    int base = cgt + cg2;
    for (int r = 0; r < (int)krem; ++r) {
      int besti = -1, bestv = 0x7fffffff;
      for (int e2 = 0; e2 < ne; ++e2) {
        int v = eqi[e2];
        if (v >= 0 && v < bestv) { bestv = v; besti = e2; }
      }
      if (besti < 0) break;
      eqi[besti] = -1;
      cand[cbase + base + r] = bestv;
    }
  }
}

// ---- K2: sort each level's selected slots by (obj desc, idx asc) = lax.top_k order ----
__global__ void __launch_bounds__(1024) k_lvlsort(const float* __restrict__ obj,
                                                  int* __restrict__ cand) {
  const int KL[5] = {1000, 1000, 1000, 1000, 768};
  const int CO[5] = {0, 1000, 2000, 3000, 4000};
  int img = blockIdx.x / 5, lvl = blockIdx.x % 5;
  int k = KL[lvl];
  int cbase = img * TOTC + CO[lvl];
  int tid = threadIdx.x;
  __shared__ unsigned long long sh[1024];
  unsigned long long key = 0ull;
  if (tid < k) {
    int idx = cand[cbase + tid];
    unsigned u = sortable_u32(obj[(size_t)img * ATOT + idx]);
    key = ((unsigned long long)u << 32) | (unsigned)(0xFFFFFFFFu - (unsigned)idx);
  }
  sh[tid] = key;
  __syncthreads();
  for (int kk = 2; kk <= 1024; kk <<= 1)
    for (int j = kk >> 1; j > 0; j >>= 1) {
      int ixj = tid ^ j;
      if (ixj > tid) {
        unsigned long long a = sh[tid], b = sh[ixj];
        bool up2 = ((tid & kk) == 0);
        if ((a < b) == up2) { sh[tid] = b; sh[ixj] = a; }
      }
      __syncthreads();
    }
  if (tid < k) {
    unsigned low = (unsigned)(sh[tid] & 0xFFFFFFFFull);
    cand[cbase + tid] = (int)(0xFFFFFFFFu - low);
  }
}

// ---- K3: gather + sigmoid + BoxCoder decode + clip + valid; per-image max coord ----
__global__ void __launch_bounds__(256) k_decode(const float* __restrict__ obj,
                                                const float* __restrict__ del,
                                                const float* __restrict__ anc,
                                                const int* __restrict__ cand,
                                                float* __restrict__ boxo,
                                                float* __restrict__ keyf,
                                                unsigned* __restrict__ skey,
                                                unsigned* __restrict__ maxcb) {
#pragma clang fp contract(off)
  int img = blockIdx.x;
  int c = blockIdx.y * 256 + threadIdx.x;
  float m = 0.0f;
  if (c < TOTC) {
    int a = cand[img * TOTC + c];
    float o = obj[(size_t)img * ATOT + a];
    float s = sigmoid_ref(o);
    const float* ap = anc + (size_t)a * 4;
    float a0 = ap[0], a1 = ap[1], a2 = ap[2], a3 = ap[3];
    const float* dp = del + ((size_t)img * ATOT + (size_t)a) * 4;
    float dx = dp[0], dy = dp[1], dw = dp[2], dh = dp[3];
    float wa = a2 - a0, ha = a3 - a1;
    float cxa = a0 + 0.5f * wa, cya = a1 + 0.5f * ha;
    dw = fminf(dw, 4.135166556742356f);
    dh = fminf(dh, 4.135166556742356f);
    float cx = dx * wa + cxa;
    float cy = dy * ha + cya;
    float w = exp_xla(dw) * wa;
    float h = exp_xla(dh) * ha;
    float x1 = cx - 0.5f * w, y1 = cy - 0.5f * h;
    float x2 = cx + 0.5f * w, y2 = cy + 0.5f * h;
    x1 = fminf(fmaxf(x1, 0.0f), 1024.0f);
    x2 = fminf(fmaxf(x2, 0.0f), 1024.0f);
    y1 = fminf(fmaxf(y1, 0.0f), 1024.0f);
    y2 = fminf(fmaxf(y2, 0.0f), 1024.0f);
    float ww = x2 - x1, hh = y2 - y1;
    bool valid = (ww >= 1e-3f) && (hh >= 1e-3f) && (s >= 0.0f);
    float kf = valid ? s : -1.0f;
    float4 bx = make_float4(x1, y1, x2, y2);
    *(float4*)(boxo + (size_t)(img * TOTC + c) * 4) = bx;
    keyf[img * TOTC + c] = kf;
    skey[img * TOTC + c] = sortable_u32(kf);
    m = fmaxf(fmaxf(x1, x2), fmaxf(y1, y2));
  }
  __shared__ float red[256];
  red[threadIdx.x] = m;
  __syncthreads();
  for (int s2 = 128; s2 > 0; s2 >>= 1) {
    if (threadIdx.x < s2) red[threadIdx.x] = fmaxf(red[threadIdx.x], red[threadIdx.x + s2]);
    __syncthreads();
  }
  if (threadIdx.x == 0) atomicMax(&maxcb[img], __float_as_uint(red[0]));
}

// ---- K4: per-image global sort: key = (score_sortable, ~slot) desc == ref stable argsort ----
__global__ void __launch_bounds__(1024) k_gsort(const unsigned* __restrict__ skey,
                                                int* __restrict__ ord) {
  int img = blockIdx.x;
  int tid = threadIdx.x;
  __shared__ unsigned long long sh[8192];  // 64 KiB
  for (int i = tid; i < 8192; i += 1024) {
    unsigned long long key = 0ull;
    if (i < TOTC) {
      unsigned u = skey[img * TOTC + i];
      key = ((unsigned long long)u << 32) | (unsigned)(0xFFFFu - i);
    }
    sh[i] = key;
  }
  __syncthreads();
  for (int kk = 2; kk <= 8192; kk <<= 1)
    for (int j = kk >> 1; j > 0; j >>= 1) {
      for (int e = tid; e < 8192; e += 1024) {
        int ixj = e ^ j;
        if (ixj > e) {
          unsigned long long a = sh[e], b = sh[ixj];
          bool up2 = ((e & kk) == 0);
          if ((a < b) == up2) { sh[e] = b; sh[ixj] = a; }
        }
      }
      __syncthreads();
    }
  for (int i = tid; i < TOTC; i += 1024) {
    unsigned low = (unsigned)(sh[i] & 0xFFFFull);
    ord[img * TOTC + i] = (int)(0xFFFFu - low);
  }
}

// ---- K5: build sorted records: offset box (batched_nms trick, exact op order), area, key, orig box ----
__global__ void __launch_bounds__(256) k_srec(const float* __restrict__ boxo,
                                              const float* __restrict__ keyf,
                                              const int* __restrict__ ord,
                                              const unsigned* __restrict__ maxcb,
                                              float* __restrict__ srec) {
#pragma clang fp contract(off)
  int img = blockIdx.x;
  int i = blockIdx.y * 256 + threadIdx.x;
  if (i >= TOTC) return;
  int p = ord[img * TOTC + i];
  int lvl = p / 1000;
  if (lvl > 4) lvl = 4;
  float4 b = *(const float4*)(boxo + (size_t)(img * TOTC + p) * 4);
  float maxc = __uint_as_float(maxcb[img]);
  float off = (float)lvl * (maxc + 1.0f);
  float ox1 = b.x + off, oy1 = b.y + off, ox2 = b.z + off, oy2 = b.w + off;
  float area = (ox2 - ox1) * (oy2 - oy1);
  float kf = keyf[img * TOTC + p];
  float* r = srec + (size_t)(img * TOTC + i) * 12;
  r[0] = ox1; r[1] = oy1; r[2] = ox2; r[3] = oy2;
  r[4] = area; r[5] = kf;
  r[6] = b.x; r[7] = b.y; r[8] = b.z; r[9] = b.w;
  r[10] = 0.0f; r[11] = 0.0f;
}

// ---- K6a: pairwise suppression bit-matrix (exact ref IoU arithmetic). Chunks jc >= itile*4 only. ----
__global__ void __launch_bounds__(256) k_iou(const float* __restrict__ srec,
                                             unsigned long long* __restrict__ mat,
                                             unsigned long long* __restrict__ validw) {
#pragma clang fp contract(off)
  const int img = blockIdx.x;
  const int itile = blockIdx.y;
  const int tid = threadIdx.x;
  const int i = itile * 256 + tid;
  const int lane = tid & 63;
  const float* sb = srec + (size_t)img * TOTC * 12;
  float ix1 = 0, iy1 = 0, ix2 = 0, iy2 = 0, ia = 0;
  bool vi = false;
  if (i < TOTC) {
    const float* r = sb + (size_t)i * 12;
    float4 b = *(const float4*)r;
    ix1 = b.x; iy1 = b.y; ix2 = b.z; iy2 = b.w;
    ia = r[4];
    vi = r[5] > -0.5f;
  }
  unsigned long long vb = __ballot(vi);
  if (lane == 0 && (i >> 6) < ROWQ) validw[img * ROWQ + (i >> 6)] = vb;

  unsigned long long* rowp = mat + ((size_t)img * TOTC + (size_t)(i < TOTC ? i : 0)) * ROWQ;
  const int jc0 = itile * 4;

  auto loadj = [&](int jc, float& jx1, float& jy1, float& jx2, float& jy2, float& ja) {
    int j = jc * 64 + lane;
    if (j < TOTC) {
      const float* r = sb + (size_t)j * 12;
      float4 b = *(const float4*)r;
      jx1 = b.x; jy1 = b.y; jx2 = b.z; jy2 = b.w;
      ja = r[4];
    } else {
      jx1 = 1e30f; jy1 = 1e30f; jx2 = -1e30f; jy2 = -1e30f; ja = 0.0f;
    }
  };
  float cx1, cy1, cx2, cy2, ca;
  loadj(jc0, cx1, cy1, cx2, cy2, ca);
  for (int jc = jc0; jc < ROWQ; ++jc) {
    float nx1, ny1, nx2, ny2, na;
    loadj(jc + 1, nx1, ny1, nx2, ny2, na);
    unsigned long long bits = 0ull;
    for (int b = 0; b < 64; ++b) {
      float jx1 = __shfl(cx1, b), jy1 = __shfl(cy1, b);
      float jx2 = __shfl(cx2, b), jy2 = __shfl(cy2, b);
      float ja = __shfl(ca, b);
      float ltx = fmaxf(ix1, jx1), lty = fmaxf(iy1, jy1);
      float rbx = fminf(ix2, jx2), rby = fminf(iy2, jy2);
      float w = fmaxf(rbx - ltx, 0.0f), h = fmaxf(rby - lty, 0.0f);
      float inter = w * h;
      float uni = (ia + ja) - inter;
      bool sup = (uni > 0.0f) && (inter / uni > NMS_THR);
      if (sup) bits |= (1ull << b);
    }
    if (i < TOTC) rowp[jc] = bits;
    cx1 = nx1; cy1 = ny1; cx2 = nx2; cy2 = ny2; ca = na;
  }
}

// ---- K6b: greedy resolve over bitmasks, one wave per image, depth-3 row prefetch pipeline ----
__global__ void __launch_bounds__(64) k_resolve(const unsigned long long* __restrict__ mat,
                                                const unsigned long long* __restrict__ validw,
                                                const float* __restrict__ srec,
                                                float* __restrict__ out) {
  const int img = blockIdx.x;
  const int lane = threadIdx.x;
  __shared__ unsigned long long rem[80];
  __shared__ unsigned long long vw[80];
  for (int t = lane; t < 80; t += 64) {
    rem[t] = 0ull;
    vw[t] = (t < ROWQ) ? validw[img * ROWQ + t] : 0ull;
  }
  __syncthreads();
  const unsigned long long* matb = mat + (size_t)img * TOTC * ROWQ;
  const float* sb = srec + (size_t)img * TOTC * 12;
  float* ob = out + (size_t)img * POSTN * 4;
  float* os = out + (size_t)NIMG * POSTN * 4 + (size_t)img * POSTN;

  int vwi = 0;
  unsigned long long vbits = vw[0];
  auto nextv = [&]() -> int {
    while (vbits == 0ull) {
      if (++vwi >= ROWQ) return -1;
      vbits = vw[vwi];
    }
    int b = __builtin_ctzll(vbits);
    vbits &= vbits - 1ull;
    return vwi * 64 + b;
  };
  auto issue = [&](int i, unsigned long long& m0, unsigned long long& m1, float& od) {
    m0 = 0ull; m1 = 0ull; od = 0.0f;
    if (i < 0) return;
    const unsigned long long* row = matb + (size_t)i * ROWQ;
    m0 = row[lane];
    if (lane < ROWQ - 64) m1 = row[64 + lane];
    const float* rec = sb + (size_t)i * 12;
    if (lane < 4) od = rec[6 + lane];
    else if (lane == 4) od = rec[5];
  };
  int i0 = nextv(), i1, i2;
  unsigned long long a0, a1, b0, b1, c0, c1;
  float o0, o1, o2;
  issue(i0, a0, a1, o0);
  i1 = nextv(); issue(i1, b0, b1, o1);
  i2 = nextv(); issue(i2, c0, c1, o2);
  int c = 0;
  while (i0 >= 0 && c < POSTN) {
    int w = i0 >> 6;
    unsigned long long bit = 1ull << (i0 & 63);
    if (!(rem[w] & bit)) {
      rem[lane] |= a0;
      if (lane < ROWQ - 64) rem[64 + lane] |= a1;
      if (lane < 4) ob[(size_t)c * 4 + lane] = o0;
      else if (lane == 4) os[c] = o0;
      __syncthreads();
      ++c;
    }
    i0 = i1; a0 = b0; a1 = b1; o0 = o1;
    i1 = i2; b0 = c0; b1 = c1; o1 = o2;
    i2 = nextv(); issue(i2, c0, c1, o2);
  }
}

extern "C" void kernel_launch(void* const* d_in, const int* in_sizes, int n_in,
                              void* d_out, int out_size, void* d_ws, size_t ws_size,
                              hipStream_t stream) {
  const float* obj = (const float*)d_in[0];
  const float* del = (const float*)d_in[1];
  const float* anc = (const float*)d_in[2];
  float* out = (float*)d_out;

  char* w = (char*)d_ws;
  size_t o = 0;
  auto carve = [&](size_t bytes) -> char* {
    char* p = w + o;
    o = (o + bytes + 255) & ~(size_t)255;
    return p;
  };
  int* cand = (int*)carve((size_t)NIMG * TOTC * 4);
  unsigned* skey = (unsigned*)carve((size_t)NIMG * TOTC * 4);
  float* keyf = (float*)carve((size_t)NIMG * TOTC * 4);
  int* ord = (int*)carve((size_t)NIMG * TOTC * 4);
  float* boxo = (float*)carve((size_t)NIMG * TOTC * 16);
  float* srec = (float*)carve((size_t)NIMG * TOTC * 48);
  unsigned* maxcb = (unsigned*)carve(64);
  unsigned* hist = (unsigned*)carve((size_t)64 * 256 * 4);      // 64 KiB
  unsigned* thr = (unsigned*)carve((size_t)64 * 2 * 4);
  unsigned* cnt = (unsigned*)carve((size_t)64 * 2 * 4);
  int* eqbuf = (int*)carve((size_t)64 * EQCAP * 4);             // 2 MiB
  unsigned long long* validw = (unsigned long long*)carve((size_t)NIMG * ROWQ * 8);
  unsigned long long* mat = (unsigned long long*)carve((size_t)NIMG * TOTC * ROWQ * 8);

  hipMemsetAsync(d_out, 0, (size_t)out_size * sizeof(float), stream);
  hipMemsetAsync(maxcb, 0, 16 * sizeof(unsigned), stream);
  hipMemsetAsync(hist, 0, (size_t)64 * 256 * 4, stream);
  hipMemsetAsync(cnt, 0, (size_t)64 * 2 * 4, stream);

  k_hist<<<16 * 17, 256, 0, stream>>>(obj, hist);
  k_thresh<<<64, 64, 0, stream>>>(hist, thr);
  k_emit<<<16 * 18, 256, 0, stream>>>(obj, thr, cand, eqbuf, cnt);
  k_refine<<<64, 256, 0, stream>>>(obj, thr, eqbuf, cnt, cand);
  k_lvlsort<<<80, 1024, 0, stream>>>(obj, cand);
  k_decode<<<dim3(16, (TOTC + 255) / 256), 256, 0, stream>>>(obj, del, anc, cand, boxo, keyf, skey, maxcb);
  k_gsort<<<16, 1024, 0, stream>>>(skey, ord);
  k_srec<<<dim3(16, (TOTC + 255) / 256), 256, 0, stream>>>(boxo, keyf, ord, maxcb, srec);
  k_iou<<<dim3(16, (TOTC + 255) / 256), 256, 0, stream>>>(srec, mat, validw);
  k_resolve<<<16, 64, 0, stream>>>(mat, validw, srec, out);
}

// Round 4
// 1051.192 us; speedup vs baseline: 1.9413x; 1.3485x over previous
//
#include <hip/hip_runtime.h>
#include <stdint.h>

#define NIMG 16
#define ATOT 261888
#define TOTC 4768
#define POSTN 1000
#define NMS_THR 0.7f
#define ROWQ 75   // qwords per suppression-matrix row (4768 bits -> 75)
#define EQCAP 8192

__device__ __forceinline__ unsigned sortable_u32(float f) {
  unsigned b = __float_as_uint(f);
  return (b & 0x80000000u) ? ~b : (b | 0x80000000u);
}

// ---- XLA CPU expf replica (Cephes constants, FMA as vsl.MulAdd)  [VERIFIED absmax 0.0] ----
__device__ __forceinline__ float exp_xla(float x) {
  float xc = fminf(x, 88.72283935546875f);
  xc = fmaxf(xc, -87.33654022216796875f);
  float n = floorf(fmaf(xc, 1.44269504088896341f, 0.5f));
  float r = fmaf(n, -0.693359375f, xc);
  r = fmaf(n, 2.12194440e-4f, r);
  float y = 1.9875691500e-4f;
  y = fmaf(y, r, 1.3981999507e-3f);
  y = fmaf(y, r, 8.3334519073e-3f);
  y = fmaf(y, r, 4.1665795894e-2f);
  y = fmaf(y, r, 1.6666665459e-1f);
  y = fmaf(y, r, 5.0000001201e-1f);
  float r2 = r * r;
  y = fmaf(y, r2, r);
  y = y + 1.0f;
  return ldexpf(y, (int)n);
}

__device__ __forceinline__ float sigmoid_ref(float x) {
#pragma clang fp contract(off)
  float e = exp_xla(-x);
  return 1.0f / (1.0f + e);
}

// Block mapping for selection passes: 17 chunks per image over levels 0..3.
__device__ __forceinline__ void chunk_map(int b, int& lvl, int& start, int& cnt) {
  if (b < 12)      { lvl = 0; start = b * 16384;        cnt = 16384; }
  else if (b < 15) { lvl = 1; start = (b - 12) * 16384; cnt = 16384; }
  else if (b == 15){ lvl = 2; start = 0;                cnt = 12288; }
  else             { lvl = 3; start = 0;                cnt = 3072;  }
}
__constant__ int d_LO[5] = {0, 196608, 245760, 258048, 261120};
__constant__ int d_CO[5] = {0, 1000, 2000, 3000, 4000};

// ---- S1: per-(img,lvl) 256-bin histogram of top-8 sortable bits ----
__global__ void __launch_bounds__(256) k_hist(const float* __restrict__ obj,
                                              unsigned* __restrict__ hist) {
  int img = blockIdx.x / 17, b = blockIdx.x % 17;
  int lvl, start, cnt;
  chunk_map(b, lvl, start, cnt);
  const float4* p4 = (const float4*)(obj + (size_t)img * ATOT + d_LO[lvl] + start);
  __shared__ unsigned h[256];
  h[threadIdx.x] = 0;
  __syncthreads();
  int nv = cnt >> 2;
  for (int i = threadIdx.x; i < nv; i += 256) {
    float4 v = p4[i];
    atomicAdd(&h[sortable_u32(v.x) >> 24], 1u);
    atomicAdd(&h[sortable_u32(v.y) >> 24], 1u);
    atomicAdd(&h[sortable_u32(v.z) >> 24], 1u);
    atomicAdd(&h[sortable_u32(v.w) >> 24], 1u);
  }
  __syncthreads();
  unsigned* gh = hist + (img * 4 + lvl) * 256;
  if (h[threadIdx.x]) atomicAdd(&gh[threadIdx.x], h[threadIdx.x]);
}

// ---- S2: per-(img,lvl) threshold bucket d0 + krem ----
__global__ void __launch_bounds__(64) k_thresh(const unsigned* __restrict__ hist,
                                               unsigned* __restrict__ thr) {
  int il = blockIdx.x;
  if (threadIdx.x != 0) return;
  const unsigned* h = hist + il * 256;
  unsigned krem = 1000, cum = 0;
  int d = 255;
  for (; d > 0; --d) {
    if (cum + h[d] >= krem) break;
    cum += h[d];
  }
  thr[il * 2] = (unsigned)d;
  thr[il * 2 + 1] = krem - cum;
}

// ---- S3: emit. bucket>d0 -> cand; bucket==d0 -> eq-list; lvl4 copy ----
__global__ void __launch_bounds__(256) k_emit(const float* __restrict__ obj,
                                              const unsigned* __restrict__ thr,
                                              int* __restrict__ cand,
                                              int* __restrict__ eqbuf,
                                              unsigned* __restrict__ cnt) {
  int img = blockIdx.x / 18, b = blockIdx.x % 18;
  if (b == 17) {
    for (int i = threadIdx.x; i < 768; i += 256)
      cand[img * TOTC + d_CO[4] + i] = d_LO[4] + i;
    return;
  }
  int lvl, start, cntn;
  chunk_map(b, lvl, start, cntn);
  int il = img * 4 + lvl;
  unsigned d0 = thr[il * 2];
  int gbase = d_LO[lvl] + start;
  const float4* p4 = (const float4*)(obj + (size_t)img * ATOT + gbase);
  int nv = cntn >> 2;
  int cbase = img * TOTC + d_CO[lvl];
  for (int i = threadIdx.x; i < nv; i += 256) {
    float4 v = p4[i];
    float vv[4] = {v.x, v.y, v.z, v.w};
#pragma unroll
    for (int c4 = 0; c4 < 4; ++c4) {
      unsigned u = sortable_u32(vv[c4]);
      unsigned d = u >> 24;
      if (d >= d0) {
        int gidx = gbase + i * 4 + c4;
        if (d > d0) {
          int s = atomicAdd(&cnt[il * 2], 1u);
          cand[cbase + s] = gidx;
        } else {
          int e = atomicAdd(&cnt[il * 2 + 1], 1u);
          if (e < EQCAP) eqbuf[il * EQCAP + e] = gidx;
        }
      }
    }
  }
}

// ---- S4: refine eq-bucket with radix rounds 1-3 ----
__global__ void __launch_bounds__(256) k_refine(const float* __restrict__ obj,
                                                const unsigned* __restrict__ thr,
                                                const int* __restrict__ eqbuf,
                                                const unsigned* __restrict__ cnt,
                                                int* __restrict__ cand) {
  int il = blockIdx.x;
  int img = il >> 2, lvl = il & 3;
  unsigned pref = thr[il * 2];
  unsigned krem = thr[il * 2 + 1];
  int neq = min((int)cnt[il * 2 + 1], EQCAP);
  int cgt = (int)cnt[il * 2];
  const float* p = obj + (size_t)img * ATOT;
  const int* eq = eqbuf + il * EQCAP;
  int cbase = img * TOTC + d_CO[lvl];
  __shared__ unsigned h[256];
  __shared__ unsigned s_pref, s_krem;
  for (int round = 1; round < 4; ++round) {
    int shift = 24 - 8 * round;
    h[threadIdx.x] = 0;
    __syncthreads();
    for (int e = threadIdx.x; e < neq; e += 256) {
      unsigned u = sortable_u32(p[eq[e]]);
      if ((u >> (shift + 8)) == pref) atomicAdd(&h[(u >> shift) & 255u], 1u);
    }
    __syncthreads();
    if (threadIdx.x == 0) {
      unsigned cum = 0;
      int d = 255;
      for (; d > 0; --d) {
        if (cum + h[d] >= krem) break;
        cum += h[d];
      }
      s_pref = (pref << 8) | (unsigned)d;
      s_krem = krem - cum;
    }
    __syncthreads();
    pref = s_pref;
    krem = s_krem;
    __syncthreads();
  }
  __shared__ int cg2, ce2;
  __shared__ int eqi[1024];
  if (threadIdx.x == 0) { cg2 = 0; ce2 = 0; }
  __syncthreads();
  for (int e = threadIdx.x; e < neq; e += 256) {
    int gidx = eq[e];
    unsigned u = sortable_u32(p[gidx]);
    if (u > pref) {
      int s = atomicAdd(&cg2, 1);
      cand[cbase + cgt + s] = gidx;
    } else if (u == pref) {
      int s2 = atomicAdd(&ce2, 1);
      if (s2 < 1024) eqi[s2] = gidx;
    }
  }
  __syncthreads();
  if (threadIdx.x == 0) {
    int ne = ce2 < 1024 ? ce2 : 1024;
    int base = cgt + cg2;
    for (int r = 0; r < (int)krem; ++r) {
      int besti = -1, bestv = 0x7fffffff;
      for (int e2 = 0; e2 < ne; ++e2) {
        int v = eqi[e2];
        if (v >= 0 && v < bestv) { bestv = v; besti = e2; }
      }
      if (besti < 0) break;
      eqi[besti] = -1;
      cand[cbase + base + r] = bestv;
    }
  }
}

// ---- K2: sort each level's selected slots by (obj desc, idx asc) ----
__global__ void __launch_bounds__(1024) k_lvlsort(const float* __restrict__ obj,
                                                  int* __restrict__ cand) {
  const int KL[5] = {1000, 1000, 1000, 1000, 768};
  const int CO[5] = {0, 1000, 2000, 3000, 4000};
  int img = blockIdx.x / 5, lvl = blockIdx.x % 5;
  int k = KL[lvl];
  int cbase = img * TOTC + CO[lvl];
  int tid = threadIdx.x;
  __shared__ unsigned long long sh[1024];
  unsigned long long key = 0ull;
  if (tid < k) {
    int idx = cand[cbase + tid];
    unsigned u = sortable_u32(obj[(size_t)img * ATOT + idx]);
    key = ((unsigned long long)u << 32) | (unsigned)(0xFFFFFFFFu - (unsigned)idx);
  }
  sh[tid] = key;
  __syncthreads();
  for (int kk = 2; kk <= 1024; kk <<= 1)
    for (int j = kk >> 1; j > 0; j >>= 1) {
      int ixj = tid ^ j;
      if (ixj > tid) {
        unsigned long long a = sh[tid], b = sh[ixj];
        bool up2 = ((tid & kk) == 0);
        if ((a < b) == up2) { sh[tid] = b; sh[ixj] = a; }
      }
      __syncthreads();
    }
  if (tid < k) {
    unsigned low = (unsigned)(sh[tid] & 0xFFFFFFFFull);
    cand[cbase + tid] = (int)(0xFFFFFFFFu - low);
  }
}

// ---- K3: gather + sigmoid + BoxCoder decode + clip + valid; per-image max coord ----
__global__ void __launch_bounds__(256) k_decode(const float* __restrict__ obj,
                                                const float* __restrict__ del,
                                                const float* __restrict__ anc,
                                                const int* __restrict__ cand,
                                                float* __restrict__ boxo,
                                                float* __restrict__ keyf,
                                                unsigned* __restrict__ skey,
                                                unsigned* __restrict__ maxcb) {
#pragma clang fp contract(off)
  int img = blockIdx.x;
  int c = blockIdx.y * 256 + threadIdx.x;
  float m = 0.0f;
  if (c < TOTC) {
    int a = cand[img * TOTC + c];
    float o = obj[(size_t)img * ATOT + a];
    float s = sigmoid_ref(o);
    const float* ap = anc + (size_t)a * 4;
    float a0 = ap[0], a1 = ap[1], a2 = ap[2], a3 = ap[3];
    const float* dp = del + ((size_t)img * ATOT + (size_t)a) * 4;
    float dx = dp[0], dy = dp[1], dw = dp[2], dh = dp[3];
    float wa = a2 - a0, ha = a3 - a1;
    float cxa = a0 + 0.5f * wa, cya = a1 + 0.5f * ha;
    dw = fminf(dw, 4.135166556742356f);
    dh = fminf(dh, 4.135166556742356f);
    float cx = dx * wa + cxa;
    float cy = dy * ha + cya;
    float w = exp_xla(dw) * wa;
    float h = exp_xla(dh) * ha;
    float x1 = cx - 0.5f * w, y1 = cy - 0.5f * h;
    float x2 = cx + 0.5f * w, y2 = cy + 0.5f * h;
    x1 = fminf(fmaxf(x1, 0.0f), 1024.0f);
    x2 = fminf(fmaxf(x2, 0.0f), 1024.0f);
    y1 = fminf(fmaxf(y1, 0.0f), 1024.0f);
    y2 = fminf(fmaxf(y2, 0.0f), 1024.0f);
    float ww = x2 - x1, hh = y2 - y1;
    bool valid = (ww >= 1e-3f) && (hh >= 1e-3f) && (s >= 0.0f);
    float kf = valid ? s : -1.0f;
    float4 bx = make_float4(x1, y1, x2, y2);
    *(float4*)(boxo + (size_t)(img * TOTC + c) * 4) = bx;
    keyf[img * TOTC + c] = kf;
    skey[img * TOTC + c] = sortable_u32(kf);
    m = fmaxf(fmaxf(x1, x2), fmaxf(y1, y2));
  }
  __shared__ float red[256];
  red[threadIdx.x] = m;
  __syncthreads();
  for (int s2 = 128; s2 > 0; s2 >>= 1) {
    if (threadIdx.x < s2) red[threadIdx.x] = fmaxf(red[threadIdx.x], red[threadIdx.x + s2]);
    __syncthreads();
  }
  if (threadIdx.x == 0) atomicMax(&maxcb[img], __float_as_uint(red[0]));
}

// ---- K4: per-image global sort: key = (score_sortable, ~slot) desc ----
__global__ void __launch_bounds__(1024) k_gsort(const unsigned* __restrict__ skey,
                                                int* __restrict__ ord) {
  int img = blockIdx.x;
  int tid = threadIdx.x;
  __shared__ unsigned long long sh[8192];  // 64 KiB
  for (int i = tid; i < 8192; i += 1024) {
    unsigned long long key = 0ull;
    if (i < TOTC) {
      unsigned u = skey[img * TOTC + i];
      key = ((unsigned long long)u << 32) | (unsigned)(0xFFFFu - i);
    }
    sh[i] = key;
  }
  __syncthreads();
  for (int kk = 2; kk <= 8192; kk <<= 1)
    for (int j = kk >> 1; j > 0; j >>= 1) {
      for (int e = tid; e < 8192; e += 1024) {
        int ixj = e ^ j;
        if (ixj > e) {
          unsigned long long a = sh[e], b = sh[ixj];
          bool up2 = ((e & kk) == 0);
          if ((a < b) == up2) { sh[e] = b; sh[ixj] = a; }
        }
      }
      __syncthreads();
    }
  for (int i = tid; i < TOTC; i += 1024) {
    unsigned low = (unsigned)(sh[i] & 0xFFFFull);
    ord[img * TOTC + i] = (int)(0xFFFFu - low);
  }
}

// ---- K5: build sorted records ----
__global__ void __launch_bounds__(256) k_srec(const float* __restrict__ boxo,
                                              const float* __restrict__ keyf,
                                              const int* __restrict__ ord,
                                              const unsigned* __restrict__ maxcb,
                                              float* __restrict__ srec) {
#pragma clang fp contract(off)
  int img = blockIdx.x;
  int i = blockIdx.y * 256 + threadIdx.x;
  if (i >= TOTC) return;
  int p = ord[img * TOTC + i];
  int lvl = p / 1000;
  if (lvl > 4) lvl = 4;
  float4 b = *(const float4*)(boxo + (size_t)(img * TOTC + p) * 4);
  float maxc = __uint_as_float(maxcb[img]);
  float off = (float)lvl * (maxc + 1.0f);
  float ox1 = b.x + off, oy1 = b.y + off, ox2 = b.z + off, oy2 = b.w + off;
  float area = (ox2 - ox1) * (oy2 - oy1);
  float kf = keyf[img * TOTC + p];
  float* r = srec + (size_t)(img * TOTC + i) * 12;
  r[0] = ox1; r[1] = oy1; r[2] = ox2; r[3] = oy2;
  r[4] = area; r[5] = kf;
  r[6] = b.x; r[7] = b.y; r[8] = b.z; r[9] = b.w;
  r[10] = 0.0f; r[11] = 0.0f;
}

// ---- K6a (restructured): suppression bit-matrix, flattened balanced tasks.
// One block = (img, itile, group of 4 j-chunks). Groups per itile t = 19-t; 190/image; 3040 blocks.
// j-records staged in LDS, read at uniform address (broadcast). IoU arithmetic byte-identical
// to the verified round-2 kernel. Only chunks jc >= itile*4 are written (same invariant).
__global__ void __launch_bounds__(256) k_iou(const float* __restrict__ srec,
                                             unsigned long long* __restrict__ mat,
                                             unsigned long long* __restrict__ validw) {
#pragma clang fp contract(off)
  int gb = blockIdx.x;
  int img = gb / 190;
  int g = gb % 190;
  int t = 0, cum = 0;
  while (cum + (19 - t) <= g) { cum += 19 - t; ++t; }  // <=19 scalar iters
  int jcg = g - cum;
  int jcbase = t * 4 + jcg * 4;

  const int tid = threadIdx.x;
  const int i = t * 256 + tid;
  const int lane = tid & 63;
  const float* sb = srec + (size_t)img * TOTC * 12;

  __shared__ float4 s_box[256];
  __shared__ float s_area[256];
  {
    int j = jcbase * 64 + tid;
    if (j < TOTC) {
      const float* r = sb + (size_t)j * 12;
      s_box[tid] = *(const float4*)r;
      s_area[tid] = r[4];
    } else {
      s_box[tid] = make_float4(1e30f, 1e30f, -1e30f, -1e30f);
      s_area[tid] = 0.0f;
    }
  }

  float ix1 = 0, iy1 = 0, ix2 = 0, iy2 = 0, ia = 0;
  bool vi = false;
  if (i < TOTC) {
    const float* r = sb + (size_t)i * 12;
    float4 b = *(const float4*)r;
    ix1 = b.x; iy1 = b.y; ix2 = b.z; iy2 = b.w;
    ia = r[4];
    vi = r[5] > -0.5f;
  }
  if (jcg == 0) {  // this itile's first group writes the valid ballot words
    unsigned long long vb = __ballot(vi);
    if (lane == 0 && (i >> 6) < ROWQ) validw[img * ROWQ + (i >> 6)] = vb;
  }
  __syncthreads();

  unsigned long long* rowp = mat + ((size_t)img * TOTC + (size_t)(i < TOTC ? i : 0)) * ROWQ;
#pragma unroll
  for (int kk = 0; kk < 4; ++kk) {
    int jc = jcbase + kk;
    if (jc >= ROWQ) break;
    unsigned long long bits = 0ull;
    for (int b = 0; b < 64; ++b) {
      float4 jb = s_box[kk * 64 + b];   // uniform address -> LDS broadcast
      float ja = s_area[kk * 64 + b];
      float ltx = fmaxf(ix1, jb.x), lty = fmaxf(iy1, jb.y);
      float rbx = fminf(ix2, jb.z), rby = fminf(iy2, jb.w);
      float w = fmaxf(rbx - ltx, 0.0f), h = fmaxf(rby - lty, 0.0f);
      float inter = w * h;
      float uni = (ia + ja) - inter;
      bool sup = (uni > 0.0f) && (inter / uni > NMS_THR);
      if (sup) bits |= (1ull << b);
    }
    if (i < TOTC) rowp[jc] = bits;
  }
}

// ---- K6b: greedy resolve over bitmasks, one wave per image ----
__global__ void __launch_bounds__(64) k_resolve(const unsigned long long* __restrict__ mat,
                                                const unsigned long long* __restrict__ validw,
                                                const float* __restrict__ srec,
                                                float* __restrict__ out) {
  const int img = blockIdx.x;
  const int lane = threadIdx.x;
  __shared__ unsigned long long rem[80];
  __shared__ unsigned long long vw[80];
  for (int t = lane; t < 80; t += 64) {
    rem[t] = 0ull;
    vw[t] = (t < ROWQ) ? validw[img * ROWQ + t] : 0ull;
  }
  __syncthreads();
  const unsigned long long* matb = mat + (size_t)img * TOTC * ROWQ;
  const float* sb = srec + (size_t)img * TOTC * 12;
  float* ob = out + (size_t)img * POSTN * 4;
  float* os = out + (size_t)NIMG * POSTN * 4 + (size_t)img * POSTN;

  int vwi = 0;
  unsigned long long vbits = vw[0];
  auto nextv = [&]() -> int {
    while (vbits == 0ull) {
      if (++vwi >= ROWQ) return -1;
      vbits = vw[vwi];
    }
    int b = __builtin_ctzll(vbits);
    vbits &= vbits - 1ull;
    return vwi * 64 + b;
  };
  auto issue = [&](int i, unsigned long long& m0, unsigned long long& m1, float& od) {
    m0 = 0ull; m1 = 0ull; od = 0.0f;
    if (i < 0) return;
    const unsigned long long* row = matb + (size_t)i * ROWQ;
    m0 = row[lane];
    if (lane < ROWQ - 64) m1 = row[64 + lane];
    const float* rec = sb + (size_t)i * 12;
    if (lane < 4) od = rec[6 + lane];
    else if (lane == 4) od = rec[5];
  };
  int i0 = nextv(), i1, i2;
  unsigned long long a0, a1, b0, b1, c0, c1;
  float o0, o1, o2;
  issue(i0, a0, a1, o0);
  i1 = nextv(); issue(i1, b0, b1, o1);
  i2 = nextv(); issue(i2, c0, c1, o2);
  int c = 0;
  while (i0 >= 0 && c < POSTN) {
    int w = i0 >> 6;
    unsigned long long bit = 1ull << (i0 & 63);
    if (!(rem[w] & bit)) {
      rem[lane] |= a0;
      if (lane < ROWQ - 64) rem[64 + lane] |= a1;
      if (lane < 4) ob[(size_t)c * 4 + lane] = o0;
      else if (lane == 4) os[c] = o0;
      __syncthreads();
      ++c;
    }
    i0 = i1; a0 = b0; a1 = b1; o0 = o1;
    i1 = i2; b0 = c0; b1 = c1; o1 = o2;
    i2 = nextv(); issue(i2, c0, c1, o2);
  }
}

extern "C" void kernel_launch(void* const* d_in, const int* in_sizes, int n_in,
                              void* d_out, int out_size, void* d_ws, size_t ws_size,
                              hipStream_t stream) {
  const float* obj = (const float*)d_in[0];
  const float* del = (const float*)d_in[1];
  const float* anc = (const float*)d_in[2];
  float* out = (float*)d_out;

  char* w = (char*)d_ws;
  size_t o = 0;
  auto carve = [&](size_t bytes) -> char* {
    char* p = w + o;
    o = (o + bytes + 255) & ~(size_t)255;
    return p;
  };
  int* cand = (int*)carve((size_t)NIMG * TOTC * 4);
  unsigned* skey = (unsigned*)carve((size_t)NIMG * TOTC * 4);
  float* keyf = (float*)carve((size_t)NIMG * TOTC * 4);
  int* ord = (int*)carve((size_t)NIMG * TOTC * 4);
  float* boxo = (float*)carve((size_t)NIMG * TOTC * 16);
  float* srec = (float*)carve((size_t)NIMG * TOTC * 48);
  unsigned* maxcb = (unsigned*)carve(64);
  unsigned* hist = (unsigned*)carve((size_t)64 * 256 * 4);
  unsigned* thr = (unsigned*)carve((size_t)64 * 2 * 4);
  unsigned* cnt = (unsigned*)carve((size_t)64 * 2 * 4);
  int* eqbuf = (int*)carve((size_t)64 * EQCAP * 4);
  unsigned long long* validw = (unsigned long long*)carve((size_t)NIMG * ROWQ * 8);
  unsigned long long* mat = (unsigned long long*)carve((size_t)NIMG * TOTC * ROWQ * 8);

  hipMemsetAsync(d_out, 0, (size_t)out_size * sizeof(float), stream);
  hipMemsetAsync(maxcb, 0, 16 * sizeof(unsigned), stream);
  hipMemsetAsync(hist, 0, (size_t)64 * 256 * 4, stream);
  hipMemsetAsync(cnt, 0, (size_t)64 * 2 * 4, stream);

  k_hist<<<16 * 17, 256, 0, stream>>>(obj, hist);
  k_thresh<<<64, 64, 0, stream>>>(hist, thr);
  k_emit<<<16 * 18, 256, 0, stream>>>(obj, thr, cand, eqbuf, cnt);
  k_refine<<<64, 256, 0, stream>>>(obj, thr, eqbuf, cnt, cand);
  k_lvlsort<<<80, 1024, 0, stream>>>(obj, cand);
  k_decode<<<dim3(16, (TOTC + 255) / 256), 256, 0, stream>>>(obj, del, anc, cand, boxo, keyf, skey, maxcb);
  k_gsort<<<16, 1024, 0, stream>>>(skey, ord);
  k_srec<<<dim3(16, (TOTC + 255) / 256), 256, 0, stream>>>(boxo, keyf, ord, maxcb, srec);
  k_iou<<<16 * 190, 256, 0, stream>>>(srec, mat, validw);
  k_resolve<<<16, 64, 0, stream>>>(mat, validw, srec, out);
}